// Round 6
// baseline (87.857 us; speedup 1.0000x reference)
//
#include <hip/hip_runtime.h>

// QCNNHybridModel: fused conv2x2+sigmoid -> RBF(16) -> Linear(16,32)+tanh -> Linear(32,1)+sigmoid
// One thread per sample. B=65536, input 9x9 f32 per sample.

constexpr int NPIX    = 81;   // 9*9
constexpr int RBF_IN  = 64;   // 8*8 conv outputs
constexpr int RBF_OUT = 16;
constexpr int HID     = 32;

__device__ __forceinline__ float sigmoid_f(float v) {
    // 1/(1+exp(-v)); exp overflow gives +inf -> rcp -> 0, correct limit.
    return __builtin_amdgcn_rcpf(1.0f + __expf(-v));
}

__device__ __forceinline__ float tanh_f(float v) {
    float vc = fminf(fmaxf(v, -15.0f), 15.0f);   // avoid inf/inf
    float e  = __expf(2.0f * vc);
    return (e - 1.0f) * __builtin_amdgcn_rcpf(e + 1.0f);
}

__global__ __launch_bounds__(256, 1) void qcnn_fused(
    const float* __restrict__ x,        // [B,1,9,9]
    const float* __restrict__ conv_w,   // [1,1,2,2]
    const float* __restrict__ conv_b,   // [1]
    const float* __restrict__ centers,  // [16,64]
    const float* __restrict__ w1,       // [16,32]
    const float* __restrict__ b1,       // [32]
    const float* __restrict__ w2,       // [32,1]
    const float* __restrict__ b2,       // [1]
    float* __restrict__ out,            // [B]
    int nB)
{
    // ||a-c||^2 = ||a||^2 + a . (-2c) + ||c||^2
    __shared__ float s_c2t[RBF_IN * RBF_OUT];  // [k][j] = -2*centers[j][k]  (4 KB)
    __shared__ float s_cc[RBF_OUT];            // ||c_j||^2
    __shared__ float s_w1t[HID * RBF_OUT];     // [i][j] = w1[j][i]          (2 KB)
    __shared__ float s_b1[HID];
    __shared__ float s_w2[HID];

    const int tid = threadIdx.x;
    for (int idx = tid; idx < RBF_IN * RBF_OUT; idx += 256) {
        int k = idx >> 4, j = idx & 15;
        s_c2t[idx] = -2.0f * centers[j * RBF_IN + k];
    }
    for (int idx = tid; idx < HID * RBF_OUT; idx += 256) {
        int i = idx >> 4, j = idx & 15;
        s_w1t[idx] = w1[j * HID + i];
    }
    if (tid < HID) { s_b1[tid] = b1[tid]; s_w2[tid] = w2[tid]; }
    if (tid < RBF_OUT) {
        float s = 0.0f;
        for (int k = 0; k < RBF_IN; ++k) {
            float c = centers[tid * RBF_IN + k];
            s = fmaf(c, c, s);
        }
        s_cc[tid] = s;
    }
    __syncthreads();

    const int b = blockIdx.x * 256 + tid;
    if (b >= nB) return;

    // uniform scalar loads (compiler scalarizes)
    const float w00 = conv_w[0], w01 = conv_w[1], w10 = conv_w[2], w11 = conv_w[3];
    const float cbias = conv_b[0];

    const float* __restrict__ xp = x + (size_t)b * NPIX;
    float xr[NPIX];
    #pragma unroll
    for (int i = 0; i < NPIX; ++i) xr[i] = xp[i];

    float dot[RBF_OUT];
    #pragma unroll
    for (int j = 0; j < RBF_OUT; ++j) dot[j] = 0.0f;
    float S2 = 0.0f;

    #pragma unroll
    for (int r = 0; r < 8; ++r) {
        #pragma unroll
        for (int c = 0; c < 8; ++c) {
            float v = cbias;
            v = fmaf(w00, xr[r*9 + c],      v);
            v = fmaf(w01, xr[r*9 + c + 1],  v);
            v = fmaf(w10, xr[r*9 + 9 + c],  v);
            v = fmaf(w11, xr[r*9 + 10 + c], v);
            float a = sigmoid_f(v);               // sigmoid(logits - 0)
            S2 = fmaf(a, a, S2);
            const int k = r*8 + c;
            #pragma unroll
            for (int j = 0; j < RBF_OUT; ++j)
                dot[j] = fmaf(a, s_c2t[k*RBF_OUT + j], dot[j]);  // ds_read_b128 x4
        }
    }

    float rbf[RBF_OUT];
    #pragma unroll
    for (int j = 0; j < RBF_OUT; ++j)
        rbf[j] = __expf(-(S2 + dot[j] + s_cc[j]));   // gamma = 1

    float acc = b2[0];
    #pragma unroll
    for (int i = 0; i < HID; ++i) {
        float hv = s_b1[i];
        #pragma unroll
        for (int j = 0; j < RBF_OUT; ++j)
            hv = fmaf(rbf[j], s_w1t[i*RBF_OUT + j], hv);
        acc = fmaf(tanh_f(hv), s_w2[i], acc);
    }
    out[b] = sigmoid_f(acc);
}

extern "C" void kernel_launch(void* const* d_in, const int* in_sizes, int n_in,
                              void* d_out, int out_size, void* d_ws, size_t ws_size,
                              hipStream_t stream) {
    const float* x       = (const float*)d_in[0];
    const float* conv_w  = (const float*)d_in[1];
    const float* conv_b  = (const float*)d_in[2];
    const float* centers = (const float*)d_in[3];
    const float* w1      = (const float*)d_in[4];
    const float* b1      = (const float*)d_in[5];
    const float* w2      = (const float*)d_in[6];
    const float* b2      = (const float*)d_in[7];
    float* out = (float*)d_out;

    int nB = out_size;                 // 65536
    int grid = (nB + 255) / 256;
    qcnn_fused<<<grid, 256, 0, stream>>>(x, conv_w, conv_b, centers,
                                         w1, b1, w2, b2, out, nB);
}